// Round 4
// baseline (403.560 us; speedup 1.0000x reference)
//
#include <hip/hip_runtime.h>
#include <hip/hip_bf16.h>
#include <math.h>

// N_IN=32, N_OUT=31, H=128, npts=65536.
// Per point: X_l (128x32) propagated through Z = W_l @ X, with
// X'[:, :31] = D * Z[:, :31], X'[:, 31] = tanh(Z[:,31] + b).
// MFMA 16x16x32 bf16; wave w owns rows [16w, 16w+16) of every layer.

using short8 = __attribute__((ext_vector_type(8))) short;
using f32x4  = __attribute__((ext_vector_type(4))) float;

#define PB 4          // points per pass
#define PPB 32        // points per block
#define STRIDE 136    // ushort elems per XT row (272 B = 17*16: 16B-aligned rows)

__device__ __forceinline__ float fast_tanh(float z) {
    float e = __expf(2.0f * z);
    return 1.0f - 2.0f * __builtin_amdgcn_rcpf(e + 1.0f);
}

// pack 2 f32 -> 1 dword of 2 bf16 (v_cvt_pk_bf16_f32; no builtin on gfx950)
__device__ __forceinline__ unsigned pk2(float lo, float hi) {
    unsigned r;
    asm("v_cvt_pk_bf16_f32 %0, %1, %2" : "=v"(r) : "v"(lo), "v"(hi));
    return r;
}

__device__ __forceinline__ float bf2f(ushort u) {
    union { unsigned u; float f; } c; c.u = ((unsigned)u) << 16;
    return c.f;
}

__device__ __forceinline__ ushort f2bf1(float f) {
    union { float f; unsigned u; } v; v.f = f;
    unsigned r = v.u + 0x7fffu + ((v.u >> 16) & 1u);
    return (ushort)(r >> 16);
}

__device__ __forceinline__ short8 pack8f(const float* s) {
    union { unsigned u[4]; short8 v; } r;
    #pragma unroll
    for (int q = 0; q < 4; ++q) r.u[q] = pk2(s[2 * q], s[2 * q + 1]);
    return r.v;
}

__global__ void __launch_bounds__(512, 4)
node_mfma(const float* __restrict__ tptr,
          const float* __restrict__ y,
          const float* __restrict__ W0, const float* __restrict__ b0,
          const float* __restrict__ W1, const float* __restrict__ b1,
          const float* __restrict__ W2, const float* __restrict__ b2,
          const float* __restrict__ W3, const float* __restrict__ b3,
          float* __restrict__ out, float* __restrict__ jac, int npts) {
    __shared__ __align__(16) ushort XT[PB][32][STRIDE];  // X^T: [col c][row j]
    __shared__ __align__(16) ushort W0T[32][128];        // W0T[c][j] = W0[j][c] bf16
    __shared__ __align__(16) float  d0s[PB][128];
    __shared__ __align__(16) float  h0s[PB][128];
    __shared__ float xb[PB][32];
    __shared__ float ostage[PB][31];

    float* jstage = reinterpret_cast<float*>(&XT[0][0][0]);  // aliased: used only after XT reads done

    const int tid  = threadIdx.x;
    const int w    = tid >> 6;
    const int lane = tid & 63;
    const int r16  = lane & 15;   // A-row / B-col / D-col within tile
    const int g    = lane >> 4;   // k-octet group; D rows = 4g..4g+3
    const int j    = 16 * w + r16;

    // ---- W0^T -> LDS (bf16), once per block ----
    for (int e = tid; e < 4096; e += 512) {
        int jj = e >> 5, c = e & 31;
        W0T[c][jj] = f2bf1(W0[e]);
    }

    // ---- weights -> registers ----
    float w0f[8];   // W0[j][g*8+i] f32 (layer-0 dot)
    {
        const float4* p4 = reinterpret_cast<const float4*>(W0 + j * 32 + g * 8);
        float4 q0 = p4[0], q1 = p4[1];
        w0f[0]=q0.x; w0f[1]=q0.y; w0f[2]=q0.z; w0f[3]=q0.w;
        w0f[4]=q1.x; w0f[5]=q1.y; w0f[6]=q1.z; w0f[7]=q1.w;
    }
    short8 aW[2][4];  // A-frags W1, W2: lane holds row j, k = kc*32 + g*8 + i
    #pragma unroll
    for (int L = 0; L < 2; ++L) {
        const float* WL = L ? W2 : W1;
        #pragma unroll
        for (int kc = 0; kc < 4; ++kc) {
            float tmp[8];
            const float4* p4 = reinterpret_cast<const float4*>(WL + j * 128 + kc * 32 + g * 8);
            float4 q0 = p4[0], q1 = p4[1];
            tmp[0]=q0.x; tmp[1]=q0.y; tmp[2]=q0.z; tmp[3]=q0.w;
            tmp[4]=q1.x; tmp[5]=q1.y; tmp[6]=q1.z; tmp[7]=q1.w;
            aW[L][kc] = pack8f(tmp);
        }
    }
    // layer 3 (padded to 32 rows): wave w -> (m=(w>>1)&1, n=w&1), points (w>>2)+{0,2}
    const int mw = (w >> 1) & 1, nw = w & 1;
    const int r3 = 16 * mw + r16;
    short8 aW3[4];
    #pragma unroll
    for (int kc = 0; kc < 4; ++kc) {
        float tmp[8];
        if (r3 < 31) {
            const float4* p4 = reinterpret_cast<const float4*>(W3 + r3 * 128 + kc * 32 + g * 8);
            float4 q0 = p4[0], q1 = p4[1];
            tmp[0]=q0.x; tmp[1]=q0.y; tmp[2]=q0.z; tmp[3]=q0.w;
            tmp[4]=q1.x; tmp[5]=q1.y; tmp[6]=q1.z; tmp[7]=q1.w;
        } else {
            #pragma unroll
            for (int i = 0; i < 8; ++i) tmp[i] = 0.0f;
        }
        aW3[kc] = pack8f(tmp);
    }
    const float b0v = b0[j];
    float bv[2][4], b3v[4];
    #pragma unroll
    for (int reg = 0; reg < 4; ++reg) {
        bv[0][reg] = b1[16 * w + 4 * g + reg];
        bv[1][reg] = b2[16 * w + 4 * g + reg];
        int o = 16 * mw + 4 * g + reg;
        b3v[reg] = (o < 31) ? b3[o] : 0.0f;
    }
    const float force = sinf(tptr[0]);

    for (int pass = 0; pass < PPB / PB; ++pass) {
        const int pbase = blockIdx.x * PPB + pass * PB;

        // ---- stage x ----
        if (tid < PB * 32) {
            int pl = tid >> 5, c = tid & 31;
            float v = 0.0f;
            if (pbase + pl < npts) v = (c < 31) ? y[(size_t)(pbase + pl) * 31 + c] : force;
            xb[pl][c] = v;
        }
        __syncthreads();

        // ---- layer 0: z0 = W0 @ x ; store d0, h0 ----
        #pragma unroll
        for (int pl = 0; pl < PB; ++pl) {
            float zp = 0.0f;
            #pragma unroll
            for (int i = 0; i < 8; ++i) zp = fmaf(w0f[i], xb[pl][g * 8 + i], zp);
            zp += __shfl_xor(zp, 16, 64);
            zp += __shfl_xor(zp, 32, 64);
            float h = fast_tanh(zp + b0v);
            if (g == 0) {
                h0s[pl][j] = h;
                d0s[pl][j] = 1.0f - h * h;
            }
        }
        __syncthreads();

        // ---- fill X0 = [D0*W0[:,:31] | h0] -> XT (vectorized, bank-uniform) ----
        #pragma unroll
        for (int it = 0; it < 8; ++it) {
            int idx = (it << 9) + tid;      // 0..4095
            int pl = idx >> 10, rem = idx & 1023;
            int c = rem >> 5, jq = rem & 31;  // rows 4jq..4jq+3
            float v0, v1, v2, v3;
            if (c == 31) {
                float4 hv = *reinterpret_cast<const float4*>(&h0s[pl][4 * jq]);
                v0 = hv.x; v1 = hv.y; v2 = hv.z; v3 = hv.w;
            } else {
                float4 dv = *reinterpret_cast<const float4*>(&d0s[pl][4 * jq]);
                ushort4 wv = *reinterpret_cast<const ushort4*>(&W0T[c][4 * jq]);
                v0 = bf2f(wv.x) * dv.x; v1 = bf2f(wv.y) * dv.y;
                v2 = bf2f(wv.z) * dv.z; v3 = bf2f(wv.w) * dv.w;
            }
            uint2 o; o.x = pk2(v0, v1); o.y = pk2(v2, v3);
            *reinterpret_cast<uint2*>(&XT[pl][c][4 * jq]) = o;
        }
        __syncthreads();

        // ---- layers 1, 2 ----
        #pragma unroll
        for (int L = 0; L < 2; ++L) {
            uint2 stashA[PB], stashB[PB];
            #pragma unroll
            for (int pl = 0; pl < PB; ++pl) {
                f32x4 a0 = {0.f, 0.f, 0.f, 0.f}, a1 = {0.f, 0.f, 0.f, 0.f};
                #pragma unroll
                for (int kc = 0; kc < 4; ++kc) {
                    short8 bf0 = *reinterpret_cast<const short8*>(&XT[pl][r16][kc * 32 + g * 8]);
                    short8 bf1 = *reinterpret_cast<const short8*>(&XT[pl][16 + r16][kc * 32 + g * 8]);
                    a0 = __builtin_amdgcn_mfma_f32_16x16x32_bf16(aW[L][kc], bf0, a0, 0, 0, 0);
                    a1 = __builtin_amdgcn_mfma_f32_16x16x32_bf16(aW[L][kc], bf1, a1, 0, 0, 0);
                }
                float va[4], vb[4];
                #pragma unroll
                for (int reg = 0; reg < 4; ++reg) {
                    float tv = fast_tanh(a1[reg] + bv[L][reg]);
                    float d  = 1.0f - tv * tv;
                    float dd = __shfl(d, lane | 15, 64);
                    va[reg] = dd * a0[reg];
                    vb[reg] = (r16 == 15) ? tv : dd * a1[reg];
                }
                uint2 pa, pb;
                pa.x = pk2(va[0], va[1]); pa.y = pk2(va[2], va[3]);
                pb.x = pk2(vb[0], vb[1]); pb.y = pk2(vb[2], vb[3]);
                stashA[pl] = pa; stashB[pl] = pb;
            }
            __syncthreads();  // all reads of XT done
            #pragma unroll
            for (int pl = 0; pl < PB; ++pl) {
                *reinterpret_cast<uint2*>(&XT[pl][r16][16 * w + 4 * g])      = stashA[pl];
                *reinterpret_cast<uint2*>(&XT[pl][16 + r16][16 * w + 4 * g]) = stashB[pl];
            }
            __syncthreads();
        }

        // ---- layer 3: Y = W3pad @ X2 (2 point-tasks per wave) ----
        f32x4 at[2];
        #pragma unroll
        for (int tsk = 0; tsk < 2; ++tsk) {
            int pl = (w >> 2) + tsk * 2;
            f32x4 a = {0.f, 0.f, 0.f, 0.f};
            #pragma unroll
            for (int kc = 0; kc < 4; ++kc) {
                short8 bf = *reinterpret_cast<const short8*>(&XT[pl][16 * nw + r16][kc * 32 + g * 8]);
                a = __builtin_amdgcn_mfma_f32_16x16x32_bf16(aW3[kc], bf, a, 0, 0, 0);
            }
            at[tsk] = a;
        }
        __syncthreads();  // XT reads done; jstage may alias XT now

        #pragma unroll
        for (int tsk = 0; tsk < 2; ++tsk) {
            int pl = (w >> 2) + tsk * 2;
            int c = 16 * nw + r16;
            #pragma unroll
            for (int reg = 0; reg < 4; ++reg) {
                int o = 16 * mw + 4 * g + reg;
                if (o < 31) {
                    if (c == 31)      ostage[pl][o] = at[tsk][reg] + b3v[reg];
                    else              jstage[pl * 961 + o * 31 + c] = at[tsk][reg];
                }
            }
        }
        __syncthreads();

        // ---- coalesced copy-out ----
        #pragma unroll
        for (int pl = 0; pl < PB; ++pl) {
            size_t p = (size_t)pbase + pl;
            if ((int)p < npts) {
                for (int e = tid; e < 961; e += 512)
                    jac[p * 961 + e] = jstage[pl * 961 + e];
            }
        }
        if (tid < 128) {
            int pl = tid >> 5, o = tid & 31;
            if (o < 31 && pbase + pl < npts)
                out[(size_t)(pbase + pl) * 31 + o] = ostage[pl][o];
        }
        __syncthreads();  // jstage (=XT) reused next pass
    }
}

extern "C" void kernel_launch(void* const* d_in, const int* in_sizes, int n_in,
                              void* d_out, int out_size, void* d_ws, size_t ws_size,
                              hipStream_t stream) {
    const float* t  = (const float*)d_in[0];
    const float* y  = (const float*)d_in[1];
    const float* W0 = (const float*)d_in[2];
    const float* b0 = (const float*)d_in[3];
    const float* W1 = (const float*)d_in[4];
    const float* b1 = (const float*)d_in[5];
    const float* W2 = (const float*)d_in[6];
    const float* b2 = (const float*)d_in[7];
    const float* W3 = (const float*)d_in[8];
    const float* b3 = (const float*)d_in[9];

    const int npts = in_sizes[1] / 31;  // 65536
    float* out = (float*)d_out;
    float* jac = out + (size_t)npts * 31;

    const int blocks = (npts + PPB - 1) / PPB;  // 2048
    node_mfma<<<blocks, 512, 0, stream>>>(t, y, W0, b0, W1, b1, W2, b2, W3, b3,
                                          out, jac, npts);
}

// Round 5
// 322.411 us; speedup vs baseline: 1.2517x; 1.2517x over previous
//
#include <hip/hip_runtime.h>
#include <hip/hip_bf16.h>
#include <math.h>

// N_IN=32, N_OUT=31, H=128, npts=65536.
// Per point: X_l (128x32) propagated through Z = W_l @ X, with
// X'[:, :31] = D * Z[:, :31], X'[:, 31] = tanh(Z[:,31] + b).
// MFMA 16x16x32 bf16; wave w owns rows [16w, 16w+16) of every layer.
// Schedule: double-buffered XT (L0->A, L1->B, L2->A), 4 barriers/pass,
// y prefetched one pass ahead, direct scatter stores.

using short8 = __attribute__((ext_vector_type(8))) short;
using f32x4  = __attribute__((ext_vector_type(4))) float;

#define PB 4          // points per pass
#define PPB 32        // points per block
#define STRIDE 136    // ushort elems per XT row (272 B = 17*16: 16B-aligned rows)

__device__ __forceinline__ float fast_tanh(float z) {
    float e = __expf(2.0f * z);
    return 1.0f - 2.0f * __builtin_amdgcn_rcpf(e + 1.0f);
}

// pack 2 f32 -> 1 dword of 2 bf16 (v_cvt_pk_bf16_f32; no builtin on gfx950)
__device__ __forceinline__ unsigned pk2(float lo, float hi) {
    unsigned r;
    asm("v_cvt_pk_bf16_f32 %0, %1, %2" : "=v"(r) : "v"(lo), "v"(hi));
    return r;
}

__device__ __forceinline__ ushort f2bf1(float f) {
    union { float f; unsigned u; } v; v.f = f;
    unsigned r = v.u + 0x7fffu + ((v.u >> 16) & 1u);
    return (ushort)(r >> 16);
}

__device__ __forceinline__ short8 pack8f(const float* s) {
    union { unsigned u[4]; short8 v; } r;
    #pragma unroll
    for (int q = 0; q < 4; ++q) r.u[q] = pk2(s[2 * q], s[2 * q + 1]);
    return r.v;
}

__global__ void __launch_bounds__(512, 4)
node_mfma(const float* __restrict__ tptr,
          const float* __restrict__ y,
          const float* __restrict__ W0, const float* __restrict__ b0,
          const float* __restrict__ W1, const float* __restrict__ b1,
          const float* __restrict__ W2, const float* __restrict__ b2,
          const float* __restrict__ W3, const float* __restrict__ b3,
          float* __restrict__ out, float* __restrict__ jac, int npts) {
    // XT[buf][point][col c][row j]; buf0 holds X0/X2, buf1 holds X1
    __shared__ __align__(16) ushort XT[2][PB][32][STRIDE];
    __shared__ float xb[PB][32];

    const int tid  = threadIdx.x;
    const int w    = tid >> 6;
    const int lane = tid & 63;
    const int r16  = lane & 15;   // A-row / B-col / D-col within tile
    const int g    = lane >> 4;   // k-octet group; D rows = 4g..4g+3
    const int j    = 16 * w + r16;

    // ---- weights -> registers ----
    float w0f[8];   // W0[j][g*8+i] f32 (layer-0 dot + X0 build)
    {
        const float4* p4 = reinterpret_cast<const float4*>(W0 + j * 32 + g * 8);
        float4 q0 = p4[0], q1 = p4[1];
        w0f[0]=q0.x; w0f[1]=q0.y; w0f[2]=q0.z; w0f[3]=q0.w;
        w0f[4]=q1.x; w0f[5]=q1.y; w0f[6]=q1.z; w0f[7]=q1.w;
    }
    short8 aW[2][4];  // A-frags W1, W2: lane holds row j, k = kc*32 + g*8 + i
    #pragma unroll
    for (int L = 0; L < 2; ++L) {
        const float* WL = L ? W2 : W1;
        #pragma unroll
        for (int kc = 0; kc < 4; ++kc) {
            float tmp[8];
            const float4* p4 = reinterpret_cast<const float4*>(WL + j * 128 + kc * 32 + g * 8);
            float4 q0 = p4[0], q1 = p4[1];
            tmp[0]=q0.x; tmp[1]=q0.y; tmp[2]=q0.z; tmp[3]=q0.w;
            tmp[4]=q1.x; tmp[5]=q1.y; tmp[6]=q1.z; tmp[7]=q1.w;
            aW[L][kc] = pack8f(tmp);
        }
    }
    // layer 3 (padded to 32 rows): wave w -> (m=(w>>1)&1, n=w&1), points (w>>2)+{0,2}
    const int mw = (w >> 1) & 1, nw = w & 1;
    const int r3 = 16 * mw + r16;
    short8 aW3[4];
    #pragma unroll
    for (int kc = 0; kc < 4; ++kc) {
        float tmp[8];
        if (r3 < 31) {
            const float4* p4 = reinterpret_cast<const float4*>(W3 + r3 * 128 + kc * 32 + g * 8);
            float4 q0 = p4[0], q1 = p4[1];
            tmp[0]=q0.x; tmp[1]=q0.y; tmp[2]=q0.z; tmp[3]=q0.w;
            tmp[4]=q1.x; tmp[5]=q1.y; tmp[6]=q1.z; tmp[7]=q1.w;
        } else {
            #pragma unroll
            for (int i = 0; i < 8; ++i) tmp[i] = 0.0f;
        }
        aW3[kc] = pack8f(tmp);
    }
    const float b0v = b0[j];
    float bv[2][4], b3v[4];
    #pragma unroll
    for (int reg = 0; reg < 4; ++reg) {
        bv[0][reg] = b1[16 * w + 4 * g + reg];
        bv[1][reg] = b2[16 * w + 4 * g + reg];
        int o = 16 * mw + 4 * g + reg;
        b3v[reg] = (o < 31) ? b3[o] : 0.0f;
    }
    const float force = sinf(tptr[0]);

    // ---- y prefetch for pass 0 ----
    const int pl0 = tid >> 5, c0 = tid & 31;
    const bool act = tid < PB * 32;
    float pf = 0.0f;
    if (act && c0 < 31) pf = y[(size_t)(blockIdx.x * PPB + pl0) * 31 + c0];

    for (int pass = 0; pass < PPB / PB; ++pass) {
        const int pbase = blockIdx.x * PPB + pass * PB;

        // ---- publish x for this pass (from prefetch regs) ----
        if (act) xb[pl0][c0] = (c0 < 31) ? pf : force;
        __syncthreads();  // [E] xb ready; prev-pass XT[0] reads done

        // ---- layer 0: X0 = [D0*W0[:,:31] | h0] -> XT[0] ----
        #pragma unroll
        for (int pl = 0; pl < PB; ++pl) {
            float zp = 0.0f;
            #pragma unroll
            for (int i = 0; i < 8; ++i) zp = fmaf(w0f[i], xb[pl][g * 8 + i], zp);
            zp += __shfl_xor(zp, 16, 64);
            zp += __shfl_xor(zp, 32, 64);
            float h = fast_tanh(zp + b0v);
            float d = 1.0f - h * h;
            #pragma unroll
            for (int i = 0; i < 8; ++i) {
                int c = g * 8 + i;
                XT[0][pl][c][j] = f2bf1((c == 31) ? h : d * w0f[i]);
            }
        }

        // ---- issue y prefetch for next pass (hides under layers 1-3) ----
        if (act && c0 < 31 && pass + 1 < PPB / PB)
            pf = y[(size_t)(pbase + PB + pl0) * 31 + c0];

        __syncthreads();  // [A] X0 ready

        // ---- layers 1, 2: src XT[L] -> dst XT[1-L] ----
        #pragma unroll
        for (int L = 0; L < 2; ++L) {
            #pragma unroll
            for (int pl = 0; pl < PB; ++pl) {
                f32x4 a0 = {0.f, 0.f, 0.f, 0.f}, a1 = {0.f, 0.f, 0.f, 0.f};
                __builtin_amdgcn_s_setprio(1);
                #pragma unroll
                for (int kc = 0; kc < 4; ++kc) {
                    short8 bf0 = *reinterpret_cast<const short8*>(&XT[L][pl][r16][kc * 32 + g * 8]);
                    short8 bf1 = *reinterpret_cast<const short8*>(&XT[L][pl][16 + r16][kc * 32 + g * 8]);
                    a0 = __builtin_amdgcn_mfma_f32_16x16x32_bf16(aW[L][kc], bf0, a0, 0, 0, 0);
                    a1 = __builtin_amdgcn_mfma_f32_16x16x32_bf16(aW[L][kc], bf1, a1, 0, 0, 0);
                }
                __builtin_amdgcn_s_setprio(0);
                float va[4], vb[4];
                #pragma unroll
                for (int reg = 0; reg < 4; ++reg) {
                    float tv = fast_tanh(a1[reg] + bv[L][reg]);
                    float d  = 1.0f - tv * tv;
                    float dd = __shfl(d, lane | 15, 64);
                    va[reg] = dd * a0[reg];
                    vb[reg] = (r16 == 15) ? tv : dd * a1[reg];
                }
                uint2 pa, pb;
                pa.x = pk2(va[0], va[1]); pa.y = pk2(va[2], va[3]);
                pb.x = pk2(vb[0], vb[1]); pb.y = pk2(vb[2], vb[3]);
                // write to the OTHER buffer: no read-hazard, no stash needed
                *reinterpret_cast<uint2*>(&XT[1 - L][pl][r16][16 * w + 4 * g])      = pa;
                *reinterpret_cast<uint2*>(&XT[1 - L][pl][16 + r16][16 * w + 4 * g]) = pb;
            }
            __syncthreads();  // [B]/[C] X_{L+1} ready
        }

        // ---- layer 3: Y = W3pad @ X2 (X2 in XT[0]); direct scatter stores ----
        #pragma unroll
        for (int tsk = 0; tsk < 2; ++tsk) {
            int pl = (w >> 2) + tsk * 2;
            f32x4 a = {0.f, 0.f, 0.f, 0.f};
            __builtin_amdgcn_s_setprio(1);
            #pragma unroll
            for (int kc = 0; kc < 4; ++kc) {
                short8 bf = *reinterpret_cast<const short8*>(&XT[0][pl][16 * nw + r16][kc * 32 + g * 8]);
                a = __builtin_amdgcn_mfma_f32_16x16x32_bf16(aW3[kc], bf, a, 0, 0, 0);
            }
            __builtin_amdgcn_s_setprio(0);
            size_t p = (size_t)(pbase + pl);
            int c = 16 * nw + r16;
            if ((int)p < npts) {
                #pragma unroll
                for (int reg = 0; reg < 4; ++reg) {
                    int o = 16 * mw + 4 * g + reg;
                    if (o < 31) {
                        if (c == 31) out[p * 31 + o] = a[reg] + b3v[reg];
                        else         jac[(p * 31 + o) * 31 + c] = a[reg];
                    }
                }
            }
        }
        // no barrier here: loop-top [E] separates XT[0] reads from next L0 writes
    }
}

extern "C" void kernel_launch(void* const* d_in, const int* in_sizes, int n_in,
                              void* d_out, int out_size, void* d_ws, size_t ws_size,
                              hipStream_t stream) {
    const float* t  = (const float*)d_in[0];
    const float* y  = (const float*)d_in[1];
    const float* W0 = (const float*)d_in[2];
    const float* b0 = (const float*)d_in[3];
    const float* W1 = (const float*)d_in[4];
    const float* b1 = (const float*)d_in[5];
    const float* W2 = (const float*)d_in[6];
    const float* b2 = (const float*)d_in[7];
    const float* W3 = (const float*)d_in[8];
    const float* b3 = (const float*)d_in[9];

    const int npts = in_sizes[1] / 31;  // 65536
    float* out = (float*)d_out;
    float* jac = out + (size_t)npts * 31;

    const int blocks = (npts + PPB - 1) / PPB;  // 2048
    node_mfma<<<blocks, 512, 0, stream>>>(t, y, W0, b0, W1, b1, W2, b2, W3, b3,
                                          out, jac, npts);
}